// Round 1
// baseline (226.291 us; speedup 1.0000x reference)
//
#include <hip/hip_runtime.h>
#include <hip/hip_fp16.h>

// Problem constants
#define NV   20000
#define KK   3
#define INF  150
#define HH   64
#define OO   128
#define PT   80
#define KTOT 5120      // 80 bins * 64 h
#define XS   168       // x/W1 LDS col stride, halves (prep kernel)
#define NBIN 20        // bins per K-slice
#define CPV  33        // packed-conn vertex-dim stride (32 + 1 pad -> 2-way banks)

typedef _Float16 fh8 __attribute__((ext_vector_type(8)));   // MFMA A/B frag (4 VGPRs)
typedef __attribute__((ext_vector_type(4))) float f32x4;    // MFMA C/D frag
typedef __attribute__((ext_vector_type(8))) unsigned short u16x8;

__device__ __forceinline__ unsigned short f2h(float f) {
    return __half_as_ushort(__float2half(f));
}
__device__ __forceinline__ float h2f(unsigned short u) {
    return __half2float(__ushort_as_half(u));
}
__device__ __forceinline__ _Float16 u2h(unsigned short u) {
    union { unsigned short s; _Float16 h; } c; c.s = u; return c.h;
}

// ---------------------------------------------------------------------------
// Fused prep kernel (unchanged).
// Blocks 0..127: transpose Wg[o] -> W2 [S][o][kk] fp16 via LDS.
// Blocks 128..752: h = relu(x @ W1^T) -> fp16, 32 rows/block via MFMA.
// ---------------------------------------------------------------------------
__global__ __launch_bounds__(256) void prep_kernel(
    const float* __restrict__ Wg, const float* __restrict__ x,
    const float* __restrict__ W1, unsigned short* __restrict__ W2,
    unsigned short* __restrict__ hb) {
    __shared__ __align__(16) unsigned char smem[32256];
    const int tid = threadIdx.x;

    if (blockIdx.x < 128) {
        float* lds = (float*)smem;                 // 64*81 words
        const int o = blockIdx.x;
        const float* src = Wg + o * KTOT;
        for (int t = tid; t < KTOT; t += 256) {    // t = h*80 + bin
            int h = t / 80, bin = t - h * 80;
            lds[h * 81 + bin] = src[t];
        }
        __syncthreads();
        for (int t = tid; t < KTOT; t += 256) {    // t = k = bin*64 + h
            W2[(t >> 5) * 4096 + o * 32 + (t & 31)] =
                f2h(lds[(t & 63) * 81 + (t >> 6)]);
        }
        return;
    }

    unsigned short* xs = (unsigned short*)smem;    // 32*168
    unsigned short* ws = xs + 32 * XS;             // 64*168
    const int n0 = (blockIdx.x - 128) * 32;

    for (int e = tid; e < 32 * INF; e += 256) {
        int r = e / INF, c = e - r * INF;
        xs[r * XS + c] = f2h(x[n0 * INF + e]);
    }
    for (int e = tid; e < 32 * 18; e += 256) {
        int r = e / 18, c = e - r * 18;
        xs[r * XS + 150 + c] = 0;
    }
    for (int e = tid; e < 64 * INF; e += 256) {
        int r = e / INF, c = e - r * INF;
        ws[r * XS + c] = f2h(W1[e]);
    }
    for (int e = tid; e < 64 * 18; e += 256) {
        int r = e / 18, c = e - r * 18;
        ws[r * XS + 150 + c] = 0;
    }
    __syncthreads();

    const int wv   = tid >> 6;
    const int lane = tid & 63;
    const int q    = lane >> 4;
    const int r16  = lane & 15;
    const int o0   = wv * 16;

    f32x4 acc0 = {0.f, 0.f, 0.f, 0.f};
    f32x4 acc1 = acc0;
    #pragma unroll
    for (int s = 0; s < 5; s++) {
        const int kb = s * 32 + q * 8;
        fh8 a0 = *(const fh8*)(xs + r16 * XS + kb);
        fh8 a1 = *(const fh8*)(xs + (16 + r16) * XS + kb);
        fh8 b  = *(const fh8*)(ws + (o0 + r16) * XS + kb);
        acc0 = __builtin_amdgcn_mfma_f32_16x16x32_f16(a0, b, acc0, 0, 0, 0);
        acc1 = __builtin_amdgcn_mfma_f32_16x16x32_f16(a1, b, acc1, 0, 0, 0);
    }
    #pragma unroll
    for (int r = 0; r < 4; r++) {
        float v0 = acc0[r] > 0.f ? acc0[r] : 0.f;
        float v1 = acc1[r] > 0.f ? acc1[r] : 0.f;
        hb[(n0 + q * 4 + r) * HH + o0 + r16]      = f2h(v0);
        hb[(n0 + 16 + q * 4 + r) * HH + o0 + r16] = f2h(v1);
    }
}

// ---------------------------------------------------------------------------
// Geo kernel v11: barrier-free register-fragment gather.
// R0 theory: v10 was serialized-stall bound (MfmaUtil 12.8 + VALU 15.4 +
// est. TCP 33% + LDS 25% ~ sum, no overlap) by the per-bin barrier and the
// 56 KB/block-bin LDS round trip whose only job was transposing gathered
// rows into A-frag layout. But the 16x16x32 A-frag IS gatherable: lane
// l = (q,r16) needs row r16, cols q*8 -> 4 lanes/row x 16 B contiguous.
// So: 1-wave blocks (64 thr), wave owns 32 vertices (2 m-frags) x all
// 128 o (8 o-frags), ks-split x4 -> grid 625*4 (20000 = 625*32 exact, no
// guards). Per bin: 2 broadcast LDS conn reads ([cc][v] layout, 2-way
// banks = free), 12 direct A-frag gathers (prefetched 1 bin ahead; conn
// 2 ahead), in-lane fp16 k-combine, 16 W2 B-frag loads + 32 MFMA.
// ZERO barriers after the conn prologue -> 8 waves/CU drift freely and
// overlap TCP/VALU/MFMA. Trade: W2 streamed per-wave (2x L1/L2 delivery
// vs v10) for deleting the whole LDS patch pipeline.
// Partials unchanged: ks=0 -> fp32 d_out, ks>=1 -> fp16 parts[ks-1].
// ---------------------------------------------------------------------------
__global__ __launch_bounds__(64, 2) void geo_kernel(
    const int*   __restrict__ conn_idx, const float* __restrict__ conn_w,
    const unsigned short* __restrict__ W2, const unsigned short* __restrict__ hb,
    float* __restrict__ out, unsigned short* __restrict__ parts) {
    __shared__ __align__(16) unsigned short cp[NBIN * CPV * 8];   // 10560 B

    const int tid   = threadIdx.x;               // 0..63 (one wave)
    const int ks    = blockIdx.x & 3;            // K-slice 0..3
    const int vb    = (blockIdx.x >> 2) * 32;    // vertex tile base
    const int q     = tid >> 4;
    const int r16   = tid & 15;
    const int co    = q * 8;                     // col offset in 32-k window
    const int bbase = ks * NBIN;
    const int Sb    = ks * (NBIN * 2);           // first 32-k step

    // One-time conn pack: cp[cc][v] = [i0,i1,i2,w0,w1,w2,0,0] (u16/fp16).
    // [cc][v]-major: per-bin reads stride 16 B across r16 -> 2-way banks.
    for (int e = tid; e < 32 * NBIN; e += 64) {
        const int v = e / NBIN, cc = e - v * NBIN;
        const int gi = (vb + v) * (PT * KK) + (bbase + cc) * KK;
        u16x8 pk;
        pk[0] = (unsigned short)conn_idx[gi];
        pk[1] = (unsigned short)conn_idx[gi + 1];
        pk[2] = (unsigned short)conn_idx[gi + 2];
        pk[3] = f2h(conn_w[gi]);
        pk[4] = f2h(conn_w[gi + 1]);
        pk[5] = f2h(conn_w[gi + 2]);
        pk[6] = 0; pk[7] = 0;
        *(u16x8*)(cp + (cc * CPV + v) * 8) = pk;
    }
    __syncthreads();                             // only barrier in the kernel

    f32x4 acc[2][8];
    #pragma unroll
    for (int m = 0; m < 2; m++)
        #pragma unroll
        for (int o = 0; o < 8; o++)
            acc[m][o] = (f32x4){0.f, 0.f, 0.f, 0.f};

    fh8 gv[2][2][3];     // gathered A segments [m][s][k] for next bin
    fh8 pat[2][2];       // combined A-frags [m][s] for current bin

    auto rdconn = [&](int cc, u16x8& a, u16x8& b) {   // 2 LDS b128, broadcast
        a = *(const u16x8*)(cp + (cc * CPV + r16) * 8);
        b = *(const u16x8*)(cp + (cc * CPV + 16 + r16) * 8);
    };
    auto gath = [&](const u16x8& a, const u16x8& b) { // 12 direct A-frag gathers
        #pragma unroll
        for (int k = 0; k < 3; k++) {
            const unsigned short* pA = hb + (int)a[k] * HH + co;
            const unsigned short* pB = hb + (int)b[k] * HH + co;
            gv[0][0][k] = *(const fh8*)(pA);
            gv[0][1][k] = *(const fh8*)(pA + 32);
            gv[1][0][k] = *(const fh8*)(pB);
            gv[1][1][k] = *(const fh8*)(pB + 32);
        }
    };
    auto comb = [&](const u16x8& a, const u16x8& b) { // in-lane k-combine
        #pragma unroll
        for (int s = 0; s < 2; s++) {
            fh8 r0 = {}; fh8 r1 = {};
            #pragma unroll
            for (int k = 0; k < 3; k++) {
                const _Float16 wA = u2h(a[3 + k]);
                const _Float16 wB = u2h(b[3 + k]);
                const fh8 WA = {wA, wA, wA, wA, wA, wA, wA, wA};
                const fh8 WB = {wB, wB, wB, wB, wB, wB, wB, wB};
                r0 += gv[0][s][k] * WA;
                r1 += gv[1][s][k] * WB;
            }
            pat[0][s] = r0; pat[1][s] = r1;
        }
    };
    auto mfmap = [&](int cc) {                   // 16 W2 b128 + 32 MFMA
        const unsigned short* wp = W2 + (Sb + cc * 2) * 4096 + r16 * 32 + co;
        #pragma unroll
        for (int o = 0; o < 8; o++) {
            fh8 bf0 = *(const fh8*)(wp + o * 512);
            fh8 bf1 = *(const fh8*)(wp + 4096 + o * 512);
            acc[0][o] = __builtin_amdgcn_mfma_f32_16x16x32_f16(pat[0][0], bf0, acc[0][o], 0, 0, 0);
            acc[1][o] = __builtin_amdgcn_mfma_f32_16x16x32_f16(pat[1][0], bf0, acc[1][o], 0, 0, 0);
            acc[0][o] = __builtin_amdgcn_mfma_f32_16x16x32_f16(pat[0][1], bf1, acc[0][o], 0, 0, 0);
            acc[1][o] = __builtin_amdgcn_mfma_f32_16x16x32_f16(pat[1][1], bf1, acc[1][o], 0, 0, 0);
        }
    };

    // Pipeline: pat holds bin cc; gathers for cc+1 in flight across MFMA;
    // conn for cc+2 prefetched under the MFMA phase.
    u16x8 cA, cB, nA, nB, tA, tB;
    rdconn(0, cA, cB);
    gath(cA, cB);
    rdconn(1, nA, nB);
    comb(cA, cB);

    for (int cc = 0; cc < NBIN; cc++) {
        const bool more = (cc + 1 < NBIN);
        if (more) gath(nA, nB);                  // issue gathers early
        if (cc + 2 < NBIN) rdconn(cc + 2, tA, tB);
        mfmap(cc);                               // hide gather latency here
        if (more) { comb(nA, nB); nA = tA; nB = tB; }
    }

    // Store. D layout: row = q*4+reg, col = r16. 625*32 = 20000 -> no guards.
    if (ks == 0) {
        #pragma unroll
        for (int m = 0; m < 2; m++) {
            const int rb = vb + m * 16 + q * 4;
            #pragma unroll
            for (int o = 0; o < 8; o++)
                #pragma unroll
                for (int r = 0; r < 4; r++)
                    out[(rb + r) * OO + o * 16 + r16] = acc[m][o][r];
        }
    } else {
        unsigned short* pp = parts + (ks - 1) * (NV * OO);
        #pragma unroll
        for (int m = 0; m < 2; m++) {
            const int rb = vb + m * 16 + q * 4;
            #pragma unroll
            for (int o = 0; o < 8; o++)
                #pragma unroll
                for (int r = 0; r < 4; r++)
                    pp[(rb + r) * OO + o * 16 + r16] = f2h(acc[m][o][r]);
        }
    }
}

// ---------------------------------------------------------------------------
// Epilogue: v = part0(out) + part1+part2+part3 + bg; out = v*rsqrt(sum v^2).
// 32 rows/block, 8 threads per row. Reads then fully overwrites d_out.
// ---------------------------------------------------------------------------
__global__ __launch_bounds__(256) void norm_kernel(
    float* __restrict__ out, const unsigned short* __restrict__ parts,
    const float* __restrict__ bg) {
    const int tid = threadIdx.x;
    const int n   = blockIdx.x * 32 + (tid >> 3);
    const int l   = tid & 7;
    float v[16];
    float s = 0.f;
    #pragma unroll
    for (int i = 0; i < 16; i++) {
        const int o = i * 8 + l;
        const int e = n * OO + o;
        v[i] = out[e] + h2f(parts[e]) + h2f(parts[NV * OO + e]) +
               h2f(parts[2 * NV * OO + e]) + bg[o];
        s += v[i] * v[i];
    }
    for (int off = 4; off; off >>= 1) s += __shfl_down(s, off, 8);
    const float r = rsqrtf(__shfl(s, 0, 8));
    #pragma unroll
    for (int i = 0; i < 16; i++)
        out[n * OO + i * 8 + l] = v[i] * r;
}

// ---------------------------------------------------------------------------
extern "C" void kernel_launch(void* const* d_in, const int* in_sizes, int n_in,
                              void* d_out, int out_size, void* d_ws, size_t ws_size,
                              hipStream_t stream) {
    const float* x        = (const float*)d_in[0];
    const int*   conn_idx = (const int*)  d_in[1];
    const float* conn_w   = (const float*)d_in[2];
    const float* W1       = (const float*)d_in[3];
    const float* Wg       = (const float*)d_in[4];
    const float* bg       = (const float*)d_in[5];
    float*       out      = (float*)d_out;

    unsigned short* W2    = (unsigned short*)d_ws;         // 655,360 fp16 (1.31 MB)
    unsigned short* hb    = W2 + OO * KTOT;                // 1,280,000 fp16 (2.56 MB)
    unsigned short* parts = hb + NV * HH;                  // 3 x 2,560,000 fp16 (15.4 MB)

    hipLaunchKernelGGL(prep_kernel, dim3(128 + NV / 32), dim3(256), 0, stream,
                       Wg, x, W1, W2, hb);
    hipLaunchKernelGGL(geo_kernel, dim3(4 * (NV / 32)), dim3(64), 0, stream,
                       conn_idx, conn_w, W2, hb, out, parts);
    hipLaunchKernelGGL(norm_kernel, dim3(NV / 32), dim3(256), 0, stream,
                       out, parts, bg);
}

// Round 2
// 172.754 us; speedup vs baseline: 1.3099x; 1.3099x over previous
//
#include <hip/hip_runtime.h>
#include <hip/hip_fp16.h>

// Problem constants
#define NV   20000
#define KK   3
#define INF  150
#define HH   64
#define OO   128
#define PT   80
#define KTOT 5120      // 80 bins * 64 h
#define NB   128       // vertices per geo block (v13: doubled to halve W2 bytes/vertex)
#define RS   72        // pch v-row stride, halves (64 + 8 pad)
#define CB   (NB * RS) // 9216 halves = 18432 B per buffer
#define XS   168       // x/W1 LDS col stride, halves (prep kernel)
#define NBIN 20        // bins per K-slice

typedef _Float16 fh8 __attribute__((ext_vector_type(8)));   // MFMA A/B frag (4 VGPRs)
typedef __attribute__((ext_vector_type(4))) float f32x4;    // MFMA C/D frag
typedef __attribute__((ext_vector_type(8))) unsigned short u16x8;

__device__ __forceinline__ unsigned short f2h(float f) {
    return __half_as_ushort(__float2half(f));
}
__device__ __forceinline__ float h2f(unsigned short u) {
    return __half2float(__ushort_as_half(u));
}
__device__ __forceinline__ _Float16 u2h(unsigned short u) {
    union { unsigned short s; _Float16 h; } c; c.s = u; return c.h;
}

// ---------------------------------------------------------------------------
// Fused prep kernel (unchanged).
// Blocks 0..127: transpose Wg[o] -> W2 [S][o][kk] fp16 via LDS.
// Blocks 128..752: h = relu(x @ W1^T) -> fp16, 32 rows/block via MFMA.
// ---------------------------------------------------------------------------
__global__ __launch_bounds__(256) void prep_kernel(
    const float* __restrict__ Wg, const float* __restrict__ x,
    const float* __restrict__ W1, unsigned short* __restrict__ W2,
    unsigned short* __restrict__ hb) {
    __shared__ __align__(16) unsigned char smem[32256];
    const int tid = threadIdx.x;

    if (blockIdx.x < 128) {
        float* lds = (float*)smem;                 // 64*81 words
        const int o = blockIdx.x;
        const float* src = Wg + o * KTOT;
        for (int t = tid; t < KTOT; t += 256) {    // t = h*80 + bin
            int h = t / 80, bin = t - h * 80;
            lds[h * 81 + bin] = src[t];
        }
        __syncthreads();
        for (int t = tid; t < KTOT; t += 256) {    // t = k = bin*64 + h
            W2[(t >> 5) * 4096 + o * 32 + (t & 31)] =
                f2h(lds[(t & 63) * 81 + (t >> 6)]);
        }
        return;
    }

    unsigned short* xs = (unsigned short*)smem;    // 32*168
    unsigned short* ws = xs + 32 * XS;             // 64*168
    const int n0 = (blockIdx.x - 128) * 32;

    for (int e = tid; e < 32 * INF; e += 256) {
        int r = e / INF, c = e - r * INF;
        xs[r * XS + c] = f2h(x[n0 * INF + e]);
    }
    for (int e = tid; e < 32 * 18; e += 256) {
        int r = e / 18, c = e - r * 18;
        xs[r * XS + 150 + c] = 0;
    }
    for (int e = tid; e < 64 * INF; e += 256) {
        int r = e / INF, c = e - r * INF;
        ws[r * XS + c] = f2h(W1[e]);
    }
    for (int e = tid; e < 64 * 18; e += 256) {
        int r = e / 18, c = e - r * 18;
        ws[r * XS + 150 + c] = 0;
    }
    __syncthreads();

    const int wv   = tid >> 6;
    const int lane = tid & 63;
    const int q    = lane >> 4;
    const int r16  = lane & 15;
    const int o0   = wv * 16;

    f32x4 acc0 = {0.f, 0.f, 0.f, 0.f};
    f32x4 acc1 = acc0;
    #pragma unroll
    for (int s = 0; s < 5; s++) {
        const int kb = s * 32 + q * 8;
        fh8 a0 = *(const fh8*)(xs + r16 * XS + kb);
        fh8 a1 = *(const fh8*)(xs + (16 + r16) * XS + kb);
        fh8 b  = *(const fh8*)(ws + (o0 + r16) * XS + kb);
        acc0 = __builtin_amdgcn_mfma_f32_16x16x32_f16(a0, b, acc0, 0, 0, 0);
        acc1 = __builtin_amdgcn_mfma_f32_16x16x32_f16(a1, b, acc1, 0, 0, 0);
    }
    #pragma unroll
    for (int r = 0; r < 4; r++) {
        float v0 = acc0[r] > 0.f ? acc0[r] : 0.f;
        float v1 = acc1[r] > 0.f ? acc1[r] : 0.f;
        hb[(n0 + q * 4 + r) * HH + o0 + r16]      = f2h(v0);
        hb[(n0 + 16 + q * 4 + r) * HH + o0 + r16] = f2h(v1);
    }
}

// ---------------------------------------------------------------------------
// Geo kernel v13: NB=128 (8 waves / 512 thr), W2 reg-prefetch, split-K x4.
// R1 post-mortem: v11 (reg-gather, 1-wave blocks) regressed 80->131us:
// grid-capped residency (9.8 waves/CU) + VGPR starvation (68!) serialized
// every load at full L2 latency. Revised model: v10 ran at 20.4 B/cyc/CU
// of vector-load delivery ~ 80% of the ~25 B/cyc sustained ceiling ->
// BYTE-throughput bound, which also explains "occupancy gave nothing".
// v13 cuts bytes/CU 19%: doubling NB amortizes the 16 KB/bin W2 stream
// over 128 vertices (gathers are irreducible: full 128 B rows, used
// fully). 8 waves x 1 o-frag each; LDS 77.8 KB -> 2 blocks/CU (16 waves,
// residency unchanged). W2 B-frags double-buffered in registers one bin
// ahead (2-bin unrolled ping-pong, static indexing) so the per-bin W2
// L2 wait leaves the critical path.
// Deterministic partials: ks=0 -> fp32 d_out, ks>=1 -> fp16 parts[ks-1].
// ---------------------------------------------------------------------------
__global__ __launch_bounds__(512, 4) void geo_kernel(
    const int*   __restrict__ conn_idx, const float* __restrict__ conn_w,
    const unsigned short* __restrict__ W2, const unsigned short* __restrict__ hb,
    float* __restrict__ out, unsigned short* __restrict__ parts) {
    __shared__ __align__(16) unsigned short pch[2 * CB];       // 36864 B
    __shared__ __align__(16) unsigned short cp[NB * NBIN * 8]; // 40960 B packed conn

    const int tid  = threadIdx.x;
    const int ks   = blockIdx.x & 3;             // K-slice 0..3
    const int n0   = (blockIdx.x >> 2) * NB;
    const int wv   = tid >> 6;                   // wave 0..7 = o-frag
    const int lane = tid & 63;
    const int q    = lane >> 4;
    const int r16  = lane & 15;
    const int j8   = tid & 7;                    // 16B segment of h row
    const int v0   = tid >> 3;                   // vertex 0..63 (also v0+64)
    const int bbase = ks * NBIN;
    const int Sbase = ks * 40;                   // first 32-k step

    // One-time conn preload, packed: cp[(v*20+cc)*8] = [i0,i1,i2,w0,w1,w2,0,0]
    // Global side: thread-unit (v,cc) reads 12B contiguous -> coalesced.
    for (int e = tid; e < NB * NBIN; e += 512) {
        const int v = e / NBIN, cc = e - v * NBIN;
        const int vv = n0 + v;
        u16x8 pk = {0, 0, 0, 0, 0, 0, 0, 0};
        if (vv < NV) {
            const int g = vv * (PT * KK) + (bbase + cc) * KK;
            pk[0] = (unsigned short)conn_idx[g];
            pk[1] = (unsigned short)conn_idx[g + 1];
            pk[2] = (unsigned short)conn_idx[g + 2];
            pk[3] = f2h(conn_w[g]);
            pk[4] = f2h(conn_w[g + 1]);
            pk[5] = f2h(conn_w[g + 2]);
        }
        *(u16x8*)(cp + e * 8) = pk;
    }

    f32x4 acc[8];
    #pragma unroll
    for (int m = 0; m < 8; m++) acc[m] = (f32x4){0.f, 0.f, 0.f, 0.f};

    u16x8 pa, pb;        // packed conn for v0 and v0+64
    fh8   hva0, hva1, hva2, hvb0, hvb1, hvb2;

    auto loadg = [&](int cc) {                   // conn b128 + 6 gathers
        pa = *(const u16x8*)(cp + (v0 * NBIN + cc) * 8);
        pb = *(const u16x8*)(cp + ((v0 + 64) * NBIN + cc) * 8);
        hva0 = *(const fh8*)(hb + (int)pa[0] * HH + j8 * 8);
        hva1 = *(const fh8*)(hb + (int)pa[1] * HH + j8 * 8);
        hva2 = *(const fh8*)(hb + (int)pa[2] * HH + j8 * 8);
        hvb0 = *(const fh8*)(hb + (int)pb[0] * HH + j8 * 8);
        hvb1 = *(const fh8*)(hb + (int)pb[1] * HH + j8 * 8);
        hvb2 = *(const fh8*)(hb + (int)pb[2] * HH + j8 * 8);
    };
    auto w2ld = [&](int cc, fh8& b0, fh8& b1) {  // W2 B-frags, one bin ahead
        const unsigned short* wp =
            W2 + (Sbase + cc * 2) * 4096 + (wv * 16 + r16) * 32 + q * 8;
        b0 = *(const fh8*)(wp);
        b1 = *(const fh8*)(wp + 4096);
    };
    auto cwr = [&](unsigned short* buf) {        // combine + 2 LDS b128 writes
        const _Float16 a0 = u2h(pa[3]), a1 = u2h(pa[4]), a2 = u2h(pa[5]);
        const _Float16 b0 = u2h(pb[3]), b1 = u2h(pb[4]), b2 = u2h(pb[5]);
        const fh8 A0 = {a0, a0, a0, a0, a0, a0, a0, a0};
        const fh8 A1 = {a1, a1, a1, a1, a1, a1, a1, a1};
        const fh8 A2 = {a2, a2, a2, a2, a2, a2, a2, a2};
        const fh8 B0 = {b0, b0, b0, b0, b0, b0, b0, b0};
        const fh8 B1 = {b1, b1, b1, b1, b1, b1, b1, b1};
        const fh8 B2 = {b2, b2, b2, b2, b2, b2, b2, b2};
        fh8 ra = hva0 * A0 + hva1 * A1 + hva2 * A2;
        fh8 rb = hvb0 * B0 + hvb1 * B1 + hvb2 * B2;
        *(fh8*)(buf + v0 * RS + j8 * 8)        = ra;
        *(fh8*)(buf + (v0 + 64) * RS + j8 * 8) = rb;
    };
    auto mfmaph = [&](const unsigned short* buf, fh8 w0, fh8 w1) { // 16 MFMA
        #pragma unroll
        for (int s = 0; s < 2; s++) {
            const int ao = s * 32 + q * 8;
            const fh8 bf = s ? w1 : w0;
            #pragma unroll
            for (int m = 0; m < 8; m++) {
                fh8 af = *(const fh8*)(buf + (m * 16 + r16) * RS + ao);
                acc[m] = __builtin_amdgcn_mfma_f32_16x16x32_f16(af, bf, acc[m], 0, 0, 0);
            }
        }
    };

    __syncthreads();                             // cp visible

    // Prologue: bin 0 staged into buffer 0; W2(0) into reg buffer A.
    fh8 w2a0, w2a1, w2b0, w2b1;
    loadg(0);
    w2ld(0, w2a0, w2a1);
    cwr(pch);
    __syncthreads();

    // 2-bin unrolled main loop: static W2 reg ping-pong (rule #20 safe).
    #pragma unroll 1
    for (int cc = 0; cc < NBIN; cc += 2) {
        // --- even bin cc: consumes buf0 + w2A, stages bin cc+1 into buf1
        loadg(cc + 1);                           // gathers in flight over MFMA
        w2ld(cc + 1, w2b0, w2b1);                // W2 for next bin, over barrier
        mfmaph(pch, w2a0, w2a1);
        cwr(pch + CB);
        __syncthreads();
        // --- odd bin cc+1: consumes buf1 + w2B, stages bin cc+2 into buf0
        if (cc + 2 < NBIN) {
            loadg(cc + 2);
            w2ld(cc + 2, w2a0, w2a1);
        }
        mfmaph(pch + CB, w2b0, w2b1);
        if (cc + 2 < NBIN) cwr(pch);
        __syncthreads();
    }

    // Partial store. D layout: row = q*4+reg, col = r16. One writer per
    // element per stage -> deterministic, pure overwrite. Guard row < NV.
    if (ks == 0) {
        #pragma unroll
        for (int m = 0; m < 8; m++) {
            const int rb = n0 + m * 16 + q * 4;
            #pragma unroll
            for (int r = 0; r < 4; r++) {
                if (rb + r < NV)
                    out[(rb + r) * OO + wv * 16 + r16] = acc[m][r];
            }
        }
    } else {
        unsigned short* pp = parts + (ks - 1) * (NV * OO);
        #pragma unroll
        for (int m = 0; m < 8; m++) {
            const int rb = n0 + m * 16 + q * 4;
            #pragma unroll
            for (int r = 0; r < 4; r++) {
                if (rb + r < NV)
                    pp[(rb + r) * OO + wv * 16 + r16] = f2h(acc[m][r]);
            }
        }
    }
}

// ---------------------------------------------------------------------------
// Epilogue: v = part0(out) + part1+part2+part3 + bg; out = v*rsqrt(sum v^2).
// 32 rows/block, 8 threads per row. Reads then fully overwrites d_out.
// ---------------------------------------------------------------------------
__global__ __launch_bounds__(256) void norm_kernel(
    float* __restrict__ out, const unsigned short* __restrict__ parts,
    const float* __restrict__ bg) {
    const int tid = threadIdx.x;
    const int n   = blockIdx.x * 32 + (tid >> 3);
    const int l   = tid & 7;
    float v[16];
    float s = 0.f;
    #pragma unroll
    for (int i = 0; i < 16; i++) {
        const int o = i * 8 + l;
        const int e = n * OO + o;
        v[i] = out[e] + h2f(parts[e]) + h2f(parts[NV * OO + e]) +
               h2f(parts[2 * NV * OO + e]) + bg[o];
        s += v[i] * v[i];
    }
    for (int off = 4; off; off >>= 1) s += __shfl_down(s, off, 8);
    const float r = rsqrtf(__shfl(s, 0, 8));
    #pragma unroll
    for (int i = 0; i < 16; i++)
        out[n * OO + i * 8 + l] = v[i] * r;
}

// ---------------------------------------------------------------------------
extern "C" void kernel_launch(void* const* d_in, const int* in_sizes, int n_in,
                              void* d_out, int out_size, void* d_ws, size_t ws_size,
                              hipStream_t stream) {
    const float* x        = (const float*)d_in[0];
    const int*   conn_idx = (const int*)  d_in[1];
    const float* conn_w   = (const float*)d_in[2];
    const float* W1       = (const float*)d_in[3];
    const float* Wg       = (const float*)d_in[4];
    const float* bg       = (const float*)d_in[5];
    float*       out      = (float*)d_out;

    unsigned short* W2    = (unsigned short*)d_ws;         // 655,360 fp16 (1.31 MB)
    unsigned short* hb    = W2 + OO * KTOT;                // 1,280,000 fp16 (2.56 MB)
    unsigned short* parts = hb + NV * HH;                  // 3 x 2,560,000 fp16 (15.4 MB)

    const int vtiles = (NV + NB - 1) / NB;                 // 157

    hipLaunchKernelGGL(prep_kernel, dim3(128 + NV / 32), dim3(256), 0, stream,
                       Wg, x, W1, W2, hb);
    hipLaunchKernelGGL(geo_kernel, dim3(4 * vtiles), dim3(512), 0, stream,
                       conn_idx, conn_w, W2, hb, out, parts);
    hipLaunchKernelGGL(norm_kernel, dim3(NV / 32), dim3(256), 0, stream,
                       out, parts, bg);
}

// Round 3
// 158.974 us; speedup vs baseline: 1.4235x; 1.0867x over previous
//
#include <hip/hip_runtime.h>
#include <hip/hip_fp16.h>

// Problem constants
#define NV   20000
#define KK   3
#define INF  150
#define HH   64
#define OO   128
#define PT   80
#define KTOT 5120      // 80 bins * 64 h
#define NB   160       // vertices per geo block (v14: 125 tiles x 4 ks = 500 blocks
                       //  <= 512 resident capacity -> SINGLE round, no tail)
#define RS   72        // pch v-row stride, halves (64 + 8 pad)
#define CB   (NB * RS) // 11520 halves = 23040 B per buffer
#define XS   168       // x/W1 LDS col stride, halves (prep kernel)
#define NBIN 20        // bins per K-slice
#define NCH  10        // bins per conn chunk (LDS holds one chunk at a time)

typedef _Float16 fh8 __attribute__((ext_vector_type(8)));   // MFMA A/B frag (4 VGPRs)
typedef __attribute__((ext_vector_type(4))) float f32x4;    // MFMA C/D frag
typedef __attribute__((ext_vector_type(8))) unsigned short u16x8;

__device__ __forceinline__ unsigned short f2h(float f) {
    return __half_as_ushort(__float2half(f));
}
__device__ __forceinline__ float h2f(unsigned short u) {
    return __half2float(__ushort_as_half(u));
}
__device__ __forceinline__ _Float16 u2h(unsigned short u) {
    union { unsigned short s; _Float16 h; } c; c.s = u; return c.h;
}

// ---------------------------------------------------------------------------
// Fused prep kernel (unchanged).
// Blocks 0..127: transpose Wg[o] -> W2 [S][o][kk] fp16 via LDS.
// Blocks 128..752: h = relu(x @ W1^T) -> fp16, 32 rows/block via MFMA.
// ---------------------------------------------------------------------------
__global__ __launch_bounds__(256) void prep_kernel(
    const float* __restrict__ Wg, const float* __restrict__ x,
    const float* __restrict__ W1, unsigned short* __restrict__ W2,
    unsigned short* __restrict__ hb) {
    __shared__ __align__(16) unsigned char smem[32256];
    const int tid = threadIdx.x;

    if (blockIdx.x < 128) {
        float* lds = (float*)smem;                 // 64*81 words
        const int o = blockIdx.x;
        const float* src = Wg + o * KTOT;
        for (int t = tid; t < KTOT; t += 256) {    // t = h*80 + bin
            int h = t / 80, bin = t - h * 80;
            lds[h * 81 + bin] = src[t];
        }
        __syncthreads();
        for (int t = tid; t < KTOT; t += 256) {    // t = k = bin*64 + h
            W2[(t >> 5) * 4096 + o * 32 + (t & 31)] =
                f2h(lds[(t & 63) * 81 + (t >> 6)]);
        }
        return;
    }

    unsigned short* xs = (unsigned short*)smem;    // 32*168
    unsigned short* ws = xs + 32 * XS;             // 64*168
    const int n0 = (blockIdx.x - 128) * 32;

    for (int e = tid; e < 32 * INF; e += 256) {
        int r = e / INF, c = e - r * INF;
        xs[r * XS + c] = f2h(x[n0 * INF + e]);
    }
    for (int e = tid; e < 32 * 18; e += 256) {
        int r = e / 18, c = e - r * 18;
        xs[r * XS + 150 + c] = 0;
    }
    for (int e = tid; e < 64 * INF; e += 256) {
        int r = e / INF, c = e - r * INF;
        ws[r * XS + c] = f2h(W1[e]);
    }
    for (int e = tid; e < 64 * 18; e += 256) {
        int r = e / 18, c = e - r * 18;
        ws[r * XS + 150 + c] = 0;
    }
    __syncthreads();

    const int wv   = tid >> 6;
    const int lane = tid & 63;
    const int q    = lane >> 4;
    const int r16  = lane & 15;
    const int o0   = wv * 16;

    f32x4 acc0 = {0.f, 0.f, 0.f, 0.f};
    f32x4 acc1 = acc0;
    #pragma unroll
    for (int s = 0; s < 5; s++) {
        const int kb = s * 32 + q * 8;
        fh8 a0 = *(const fh8*)(xs + r16 * XS + kb);
        fh8 a1 = *(const fh8*)(xs + (16 + r16) * XS + kb);
        fh8 b  = *(const fh8*)(ws + (o0 + r16) * XS + kb);
        acc0 = __builtin_amdgcn_mfma_f32_16x16x32_f16(a0, b, acc0, 0, 0, 0);
        acc1 = __builtin_amdgcn_mfma_f32_16x16x32_f16(a1, b, acc1, 0, 0, 0);
    }
    #pragma unroll
    for (int r = 0; r < 4; r++) {
        float v0 = acc0[r] > 0.f ? acc0[r] : 0.f;
        float v1 = acc1[r] > 0.f ? acc1[r] : 0.f;
        hb[(n0 + q * 4 + r) * HH + o0 + r16]      = f2h(v0);
        hb[(n0 + 16 + q * 4 + r) * HH + o0 + r16] = f2h(v1);
    }
}

// ---------------------------------------------------------------------------
// Geo kernel v14: single-round grid (NB=160, 500 blocks = 125 tiles x 4 ks).
// R2 post-mortem: v13's -19% byte cut gave 0% -- byte model falsified. The
// invariant: v10 AND v13 both ran grid/capacity = 1.22 -> ~2 rounds, the
// second a 23%-utilization tail. Elapsed ~ 2*T_block for both, which is why
// structurally different kernels timed identically (and why extra occupancy
// "gave nothing" -- it never changed round count).
// v14: 20000 = 125*160 exactly -> 500 blocks <= 512 capacity (2/CU of 512
// thr) -> ONE round. 10 m-frags/wave; store guards deleted. To fit 2
// blocks/CU LDS (71.7 KB/block): conn staged in two 10-bin chunks --
// chunk0 -> LDS at prologue, chunk1 parked in 4 regs/thread at prologue
// and drained to LDS at bin 9 behind the existing barrier (latency fully
// hidden). W2 reg ping-pong dropped (v10==v13 proved ~0 value); W2 frags
// hoisted to top of mfma phase, L2-resident.
// Deterministic partials: ks=0 -> fp32 d_out, ks>=1 -> fp16 parts[ks-1].
// ---------------------------------------------------------------------------
__global__ __launch_bounds__(512, 4) void geo_kernel(
    const int*   __restrict__ conn_idx, const float* __restrict__ conn_w,
    const unsigned short* __restrict__ W2, const unsigned short* __restrict__ hb,
    float* __restrict__ out, unsigned short* __restrict__ parts) {
    __shared__ __align__(16) unsigned short pch[2 * CB];       // 46080 B
    __shared__ __align__(16) unsigned short cp[NB * NCH * 8];  // 25600 B packed conn

    const int tid  = threadIdx.x;
    const int ks   = blockIdx.x & 3;             // K-slice 0..3
    const int n0   = (blockIdx.x >> 2) * NB;     // 0..124 * 160
    const int wv   = tid >> 6;                   // wave 0..7 = o-frag
    const int lane = tid & 63;
    const int q    = lane >> 4;
    const int r16  = lane & 15;
    const int j8   = tid & 7;                    // 16B segment of h row
    const int v0   = tid >> 3;                   // vertex 0..63 (also +64, +128)
    const bool lo  = (tid < 256);                // waves 0..3 own rows 128..159
    const int bbase = ks * NBIN;
    const int Sbase = ks * 40;                   // first 32-k step

    // Chunk 0 conn -> LDS, packed: cp[(v*NCH+cc)*8] = [i0,i1,i2,w0,w1,w2,0,0]
    for (int e = tid; e < NB * NCH; e += 512) {
        const int v = e / NCH, cc = e - v * NCH;
        const int g = (n0 + v) * (PT * KK) + (bbase + cc) * KK;
        u16x8 pk;
        pk[0] = (unsigned short)conn_idx[g];
        pk[1] = (unsigned short)conn_idx[g + 1];
        pk[2] = (unsigned short)conn_idx[g + 2];
        pk[3] = f2h(conn_w[g]);
        pk[4] = f2h(conn_w[g + 1]);
        pk[5] = f2h(conn_w[g + 2]);
        pk[6] = 0; pk[7] = 0;
        *(u16x8*)(cp + e * 8) = pk;
    }

    // Chunk 1 conn -> registers now (global latency amortized over bins 0..8),
    // drained to LDS at bin NCH-1. 1600 entries / 512 thr = 3 full + tid<64.
    u16x8 cpre0, cpre1, cpre2, cpre3 = {0, 0, 0, 0, 0, 0, 0, 0};
    {
        auto packc = [&](int e) {
            const int v = e / NCH, cc = e - v * NCH;
            const int g = (n0 + v) * (PT * KK) + (bbase + NCH + cc) * KK;
            u16x8 pk;
            pk[0] = (unsigned short)conn_idx[g];
            pk[1] = (unsigned short)conn_idx[g + 1];
            pk[2] = (unsigned short)conn_idx[g + 2];
            pk[3] = f2h(conn_w[g]);
            pk[4] = f2h(conn_w[g + 1]);
            pk[5] = f2h(conn_w[g + 2]);
            pk[6] = 0; pk[7] = 0;
            return pk;
        };
        cpre0 = packc(tid);
        cpre1 = packc(tid + 512);
        cpre2 = packc(tid + 1024);
        if (tid < NB * NCH - 1536) cpre3 = packc(tid + 1536);
    }

    f32x4 acc[10];
    #pragma unroll
    for (int m = 0; m < 10; m++) acc[m] = (f32x4){0.f, 0.f, 0.f, 0.f};

    u16x8 pa, pb, pc;    // packed conn for rows v0, v0+64, v0+128
    fh8   hva0, hva1, hva2, hvb0, hvb1, hvb2, hvc0, hvc1, hvc2;

    auto loadg = [&](int cc) {                   // conn b128 + 6..9 gathers
        const int bb = (cc >= NCH) ? cc - NCH : cc;
        pa = *(const u16x8*)(cp + (v0 * NCH + bb) * 8);
        pb = *(const u16x8*)(cp + ((v0 + 64) * NCH + bb) * 8);
        hva0 = *(const fh8*)(hb + (int)pa[0] * HH + j8 * 8);
        hva1 = *(const fh8*)(hb + (int)pa[1] * HH + j8 * 8);
        hva2 = *(const fh8*)(hb + (int)pa[2] * HH + j8 * 8);
        hvb0 = *(const fh8*)(hb + (int)pb[0] * HH + j8 * 8);
        hvb1 = *(const fh8*)(hb + (int)pb[1] * HH + j8 * 8);
        hvb2 = *(const fh8*)(hb + (int)pb[2] * HH + j8 * 8);
        if (lo) {                                // wave-uniform (waves 0..3)
            pc = *(const u16x8*)(cp + ((v0 + 128) * NCH + bb) * 8);
            hvc0 = *(const fh8*)(hb + (int)pc[0] * HH + j8 * 8);
            hvc1 = *(const fh8*)(hb + (int)pc[1] * HH + j8 * 8);
            hvc2 = *(const fh8*)(hb + (int)pc[2] * HH + j8 * 8);
        }
    };
    auto cwr = [&](unsigned short* buf) {        // combine + 2..3 LDS b128 writes
        const _Float16 a0 = u2h(pa[3]), a1 = u2h(pa[4]), a2 = u2h(pa[5]);
        const _Float16 b0 = u2h(pb[3]), b1 = u2h(pb[4]), b2 = u2h(pb[5]);
        const fh8 A0 = {a0, a0, a0, a0, a0, a0, a0, a0};
        const fh8 A1 = {a1, a1, a1, a1, a1, a1, a1, a1};
        const fh8 A2 = {a2, a2, a2, a2, a2, a2, a2, a2};
        const fh8 B0 = {b0, b0, b0, b0, b0, b0, b0, b0};
        const fh8 B1 = {b1, b1, b1, b1, b1, b1, b1, b1};
        const fh8 B2 = {b2, b2, b2, b2, b2, b2, b2, b2};
        fh8 ra = hva0 * A0 + hva1 * A1 + hva2 * A2;
        fh8 rb = hvb0 * B0 + hvb1 * B1 + hvb2 * B2;
        *(fh8*)(buf + v0 * RS + j8 * 8)        = ra;
        *(fh8*)(buf + (v0 + 64) * RS + j8 * 8) = rb;
        if (lo) {
            const _Float16 c0 = u2h(pc[3]), c1 = u2h(pc[4]), c2 = u2h(pc[5]);
            const fh8 C0 = {c0, c0, c0, c0, c0, c0, c0, c0};
            const fh8 C1 = {c1, c1, c1, c1, c1, c1, c1, c1};
            const fh8 C2 = {c2, c2, c2, c2, c2, c2, c2, c2};
            fh8 rc = hvc0 * C0 + hvc1 * C1 + hvc2 * C2;
            *(fh8*)(buf + (v0 + 128) * RS + j8 * 8) = rc;
        }
    };
    auto mfmaph = [&](const unsigned short* buf, int cc) {   // 20 MFMA
        const unsigned short* wp =
            W2 + (Sbase + cc * 2) * 4096 + (wv * 16 + r16) * 32 + q * 8;
        const fh8 bf0 = *(const fh8*)(wp);           // hoisted: both W2 frags
        const fh8 bf1 = *(const fh8*)(wp + 4096);    //   issue before ds_reads
        #pragma unroll
        for (int s = 0; s < 2; s++) {
            const int ao = s * 32 + q * 8;
            const fh8 bf = s ? bf1 : bf0;
            #pragma unroll
            for (int m = 0; m < 10; m++) {
                fh8 af = *(const fh8*)(buf + (m * 16 + r16) * RS + ao);
                acc[m] = __builtin_amdgcn_mfma_f32_16x16x32_f16(af, bf, acc[m], 0, 0, 0);
            }
        }
    };

    __syncthreads();                             // cp chunk0 visible

    // Prologue: bin 0 staged into buffer 0
    loadg(0);
    cwr(pch);
    __syncthreads();

    #pragma unroll 1
    for (int cc = 0; cc < NBIN; cc++) {
        if (cc == NCH - 1) {
            // Drain chunk1 regs -> cp. Prior barrier (end of bin NCH-2)
            // guarantees every wave finished loadg(NCH-1) reads of chunk0.
            *(u16x8*)(cp + tid * 8)          = cpre0;
            *(u16x8*)(cp + (tid + 512) * 8)  = cpre1;
            *(u16x8*)(cp + (tid + 1024) * 8) = cpre2;
            if (tid < NB * NCH - 1536)
                *(u16x8*)(cp + (tid + 1536) * 8) = cpre3;
            __syncthreads();
        }
        if (cc + 1 < NBIN) loadg(cc + 1);        // gathers in flight over MFMA
        mfmaph(&pch[(cc & 1) * CB], cc);
        if (cc + 1 < NBIN) cwr(&pch[((cc + 1) & 1) * CB]);
        __syncthreads();
    }

    // Partial store. D layout: row = q*4+reg, col = r16. 125*160 = 20000
    // exactly -> no guards. One writer per element per stage.
    if (ks == 0) {
        #pragma unroll
        for (int m = 0; m < 10; m++) {
            const int rb = n0 + m * 16 + q * 4;
            #pragma unroll
            for (int r = 0; r < 4; r++)
                out[(rb + r) * OO + wv * 16 + r16] = acc[m][r];
        }
    } else {
        unsigned short* pp = parts + (ks - 1) * (NV * OO);
        #pragma unroll
        for (int m = 0; m < 10; m++) {
            const int rb = n0 + m * 16 + q * 4;
            #pragma unroll
            for (int r = 0; r < 4; r++)
                pp[(rb + r) * OO + wv * 16 + r16] = f2h(acc[m][r]);
        }
    }
}

// ---------------------------------------------------------------------------
// Epilogue: v = part0(out) + part1+part2+part3 + bg; out = v*rsqrt(sum v^2).
// 32 rows/block, 8 threads per row. Reads then fully overwrites d_out.
// ---------------------------------------------------------------------------
__global__ __launch_bounds__(256) void norm_kernel(
    float* __restrict__ out, const unsigned short* __restrict__ parts,
    const float* __restrict__ bg) {
    const int tid = threadIdx.x;
    const int n   = blockIdx.x * 32 + (tid >> 3);
    const int l   = tid & 7;
    float v[16];
    float s = 0.f;
    #pragma unroll
    for (int i = 0; i < 16; i++) {
        const int o = i * 8 + l;
        const int e = n * OO + o;
        v[i] = out[e] + h2f(parts[e]) + h2f(parts[NV * OO + e]) +
               h2f(parts[2 * NV * OO + e]) + bg[o];
        s += v[i] * v[i];
    }
    for (int off = 4; off; off >>= 1) s += __shfl_down(s, off, 8);
    const float r = rsqrtf(__shfl(s, 0, 8));
    #pragma unroll
    for (int i = 0; i < 16; i++)
        out[n * OO + i * 8 + l] = v[i] * r;
}

// ---------------------------------------------------------------------------
extern "C" void kernel_launch(void* const* d_in, const int* in_sizes, int n_in,
                              void* d_out, int out_size, void* d_ws, size_t ws_size,
                              hipStream_t stream) {
    const float* x        = (const float*)d_in[0];
    const int*   conn_idx = (const int*)  d_in[1];
    const float* conn_w   = (const float*)d_in[2];
    const float* W1       = (const float*)d_in[3];
    const float* Wg       = (const float*)d_in[4];
    const float* bg       = (const float*)d_in[5];
    float*       out      = (float*)d_out;

    unsigned short* W2    = (unsigned short*)d_ws;         // 655,360 fp16 (1.31 MB)
    unsigned short* hb    = W2 + OO * KTOT;                // 1,280,000 fp16 (2.56 MB)
    unsigned short* parts = hb + NV * HH;                  // 3 x 2,560,000 fp16 (15.4 MB)

    hipLaunchKernelGGL(prep_kernel, dim3(128 + NV / 32), dim3(256), 0, stream,
                       Wg, x, W1, W2, hb);
    hipLaunchKernelGGL(geo_kernel, dim3(4 * (NV / NB)), dim3(512), 0, stream,
                       conn_idx, conn_w, W2, hb, out, parts);
    hipLaunchKernelGGL(norm_kernel, dim3(NV / 32), dim3(256), 0, stream,
                       out, parts, bg);
}